// Round 7
// baseline (1169.279 us; speedup 1.0000x reference)
//
#include <hip/hip_runtime.h>
#include <math.h>

#define BB 4
#define NN 1024
#define EE 768
#define HH 12
#define DD 64
#define MLPH 1536
#define RR (BB*NN)
#define SZH ((size_t)48*1024*64)   // elements per split attention array

constexpr float EPS = 1e-6f;

typedef __bf16 bf16_t;
typedef bf16_t bf16x8 __attribute__((ext_vector_type(8)));
typedef bf16_t bf16x4 __attribute__((ext_vector_type(4)));
typedef float  f32x4  __attribute__((ext_vector_type(4)));
typedef float  f32x16 __attribute__((ext_vector_type(16)));
typedef unsigned short us8 __attribute__((ext_vector_type(8)));

#define MFMA32 __builtin_amdgcn_mfma_f32_32x32x16_bf16
#define MFMA16 __builtin_amdgcn_mfma_f32_16x16x32_bf16

__device__ __forceinline__ float gelu_exact(float x){
  return 0.5f * x * (1.0f + erff(x * 0.70710678118654752440f));
}

__device__ __forceinline__ bf16x8 negv(bf16x8 v){
  us8 u = __builtin_bit_cast(us8, v);
  u ^= (unsigned short)0x8000;
  return __builtin_bit_cast(bf16x8, u);
}

__device__ __forceinline__ void split2(float f, bf16_t& h, bf16_t& l){
  h = (bf16_t)f; l = (bf16_t)(f - (float)h);
}

// split fp32x4 -> hi/lo bf16x4, store to LDS (two 8B stores)
__device__ __forceinline__ void cvtstore(bf16_t* hp, bf16_t* lp, f32x4 v){
  bf16x4 h, l;
  #pragma unroll
  for (int i=0;i<4;i++){
    float f = v[i];
    bf16_t hb = (bf16_t)f;
    h[i] = hb;
    l[i] = (bf16_t)(f - (float)hb);
  }
  *(bf16x4*)hp = h;
  *(bf16x4*)lp = l;
}

// async global->LDS, 16B per lane; lds dest must be wave-uniform (HW adds lane*16)
__device__ __forceinline__ void gload_lds16(const bf16_t* g, bf16_t* l){
  __builtin_amdgcn_global_load_lds(
      (const __attribute__((address_space(1))) void*)g,
      (__attribute__((address_space(3))) void*)l, 16, 0, 0);
}

// tiled-plane address: plane[((row>>4)*Ko + (col>>3))*128 + (row&15)*8 + (col&7)]
__device__ __forceinline__ size_t tiled_ad(int r, int c, int Ko){
  return (((size_t)(r>>4)*Ko + (c>>3))*16 + (r&15))*8 + (c&7);
}

// ---------------- complex layernorm -> 4 tiled bf16 planes ----------------
// mode 0: inI interleaved [R][E][2]; mode 1: planar inR/inIm [R][E]
__global__ __launch_bounds__(256) void cln_kernel(
    const float* __restrict__ inI,
    const float* __restrict__ inR, const float* __restrict__ inIm,
    const float* __restrict__ gamma, const float* __restrict__ beta,
    bf16_t* __restrict__ out4, int mode)
{
  const size_t PS = (size_t)RR*EE;
  int row = blockIdx.x;
  int t = threadIdx.x;
  __shared__ float sbuf[4];
  float vr[3], vi[3], mg[3];
  #pragma unroll
  for (int j=0;j<3;j++){
    int e = t + 256*j;
    float a, b;
    if (mode == 0){
      a = inI[(size_t)row*(2*EE) + 2*e];
      b = inI[(size_t)row*(2*EE) + 2*e + 1];
    } else {
      a = inR[(size_t)row*EE + e];
      b = inIm[(size_t)row*EE + e];
    }
    vr[j]=a; vi[j]=b;
    mg[j] = sqrtf(a*a + b*b + EPS);
  }
  int lane = t & 63, wv = t >> 6;
  float s = mg[0]+mg[1]+mg[2];
  #pragma unroll
  for (int o=32;o>0;o>>=1) s += __shfl_down(s, o, 64);
  if (lane==0) sbuf[wv] = s;
  __syncthreads();
  float mean = (sbuf[0]+sbuf[1]+sbuf[2]+sbuf[3]) * (1.0f/EE);
  __syncthreads();
  float v = 0.f;
  #pragma unroll
  for (int j=0;j<3;j++){ float d = mg[j]-mean; v += d*d; }
  #pragma unroll
  for (int o=32;o>0;o>>=1) v += __shfl_down(v, o, 64);
  if (lane==0) sbuf[wv] = v;
  __syncthreads();
  float var = (sbuf[0]+sbuf[1]+sbuf[2]+sbuf[3]) * (1.0f/EE);
  float inv = 1.0f / sqrtf(var + EPS);
  #pragma unroll
  for (int j=0;j<3;j++){
    int e = t + 256*j;
    float scale = ((mg[j]-mean) * inv) / (mg[j] + EPS);
    float oR = gamma[2*e]   * (vr[j]*scale) + beta[2*e];
    float oI = gamma[2*e+1] * (vi[j]*scale) + beta[2*e+1];
    bf16_t hR,lR,hI,lI;
    split2(oR,hR,lR); split2(oI,hI,lI);
    size_t ad = tiled_ad(row, e, 96);
    out4[ad]        = hR;
    out4[PS + ad]   = lR;
    out4[2*PS + ad] = hI;
    out4[3*PS + ad] = lI;
  }
}

// ---------------- complex GEMM v2: 32x32x16 MFMA, tiled-bf16 A, fp32 W ------
// A: 4 tiled bf16 planes (rh,rl,ih,il), plane stride RR*K, staged via
//    global_load_lds (1KB chunks, layout-matched). W: fp32 [OUT][K], cvt-split
//    in staging with conflict-free quarter-wave mapping.
// Block 128x128, 4 waves 2x2, each 64x64 (2x2 frags of 32x32).
// OUT_MODE: 0 planar f32, 1 interleaved f32, 2 QKV-attention split, 3 tiled bf16
template<int ACT, int RES_MODE, int OUT_MODE>
__global__ __launch_bounds__(256, 2) void cgemm_v2(
    const bf16_t* __restrict__ a4,
    const float* __restrict__ wr, const float* __restrict__ wi,
    const float* __restrict__ br_, const float* __restrict__ bi_,
    const float* __restrict__ resr, const float* __restrict__ resi,
    float* __restrict__ outr, float* __restrict__ outi,
    bf16_t* __restrict__ osplit,
    int K, int OUT)
{
  __shared__ bf16_t Al[16384];   // 4 planes x 8 panels x 4 octs x 16 rl x 8 e
  __shared__ bf16_t Bl[16384];

  const int tid = threadIdx.x;
  const int wid = tid >> 6, lane = tid & 63;
  const int rowBase = blockIdx.y * 128, colBase = blockIdx.x * 128;
  const int Ko = K >> 3;
  const size_t AS = (size_t)RR * K;

  // B staging map (conflict-free): quarter-wave writes 128B contiguous
  const int b_so = (tid >> 4) & 3;            // k-octet 0..3
  const int b_se = (tid & 1) * 4;             // elem 0 or 4
  const int b_r0 = ((tid & 15) >> 1) + 8*wid; // row 0..31 (+32*it)

  // frag coords (32x32)
  const int fr2 = lane & 31, fq2 = lane >> 5;
  const int wr0 = (wid >> 1) * 64, wc0 = (wid & 1) * 64;

  f32x16 accR[2][2], accI[2][2];
  #pragma unroll
  for (int mi=0;mi<2;mi++)
    #pragma unroll
    for (int ni=0;ni<2;ni++){ accR[mi][ni] = (f32x16)0.f; accI[mi][ni] = (f32x16)0.f; }

  f32x4 pBr[4], pBi[4];
  auto LOADB = [&](int k0){
    #pragma unroll
    for (int it=0; it<4; it++){
      size_t ro = (size_t)(colBase + b_r0 + it*32)*K + k0 + b_so*8 + b_se;
      pBr[it] = *(const f32x4*)(wr + ro);
      pBi[it] = *(const f32x4*)(wi + ro);
    }
  };
  LOADB(0);

  for (int k0 = 0; k0 < K; k0 += 32){
    const int o0 = k0 >> 3;
    __syncthreads();   // previous compute done reading LDS
    // B: split+store, conflict-free
    #pragma unroll
    for (int it=0; it<4; it++){
      int r = b_r0 + it*32;
      int off = ((r>>4)*4 + b_so)*128 + (r&15)*8 + b_se;
      cvtstore(&Bl[off],       &Bl[4096+off],  pBr[it]);
      cvtstore(&Bl[8192+off],  &Bl[12288+off], pBi[it]);
    }
    // A: async 1KB chunk loads, 8 per wave (4 planes x 2 panels)
    #pragma unroll
    for (int q=0; q<4; q++){
      #pragma unroll
      for (int s2=0; s2<2; s2++){
        int pi = wid*2 + s2;
        const bf16_t* g = a4 + (size_t)q*AS
            + ((size_t)(blockIdx.y*8 + pi)*Ko + o0)*128 + lane*8;
        gload_lds16(g, &Al[q*4096 + pi*512]);
      }
    }
    __syncthreads();   // drains ds_write + global_load_lds
    if (k0 + 32 < K) LOADB(k0 + 32);

    #pragma unroll
    for (int ks=0; ks<2; ks++){
      bf16x8 brh[2], brl[2], bih[2], bil[2];
      #pragma unroll
      for (int ni=0; ni<2; ni++){
        int panelB = (wid&1)*4 + ni*2 + (fr2>>4);
        int off = ((panelB*4 + ks*2 + fq2)*16 + (fr2&15))*8;
        brh[ni] = *(const bf16x8*)&Bl[off];
        brl[ni] = *(const bf16x8*)&Bl[4096+off];
        bih[ni] = *(const bf16x8*)&Bl[8192+off];
        bil[ni] = *(const bf16x8*)&Bl[12288+off];
      }
      #pragma unroll
      for (int mi=0; mi<2; mi++){
        int panelA = (wid>>1)*4 + mi*2 + (fr2>>4);
        int off = ((panelA*4 + ks*2 + fq2)*16 + (fr2&15))*8;
        bf16x8 arh = *(const bf16x8*)&Al[off];
        bf16x8 arl = *(const bf16x8*)&Al[4096+off];
        bf16x8 aih = *(const bf16x8*)&Al[8192+off];
        bf16x8 ail = *(const bf16x8*)&Al[12288+off];
        bf16x8 nih = negv(aih), nil_ = negv(ail);
        #pragma unroll
        for (int ni=0; ni<2; ni++){
          f32x16 cR = accR[mi][ni], cI = accI[mi][ni];
          cR = MFMA32(arh,  brh[ni], cR, 0,0,0);
          cR = MFMA32(arh,  brl[ni], cR, 0,0,0);
          cR = MFMA32(arl,  brh[ni], cR, 0,0,0);
          cR = MFMA32(nih,  bih[ni], cR, 0,0,0);
          cR = MFMA32(nih,  bil[ni], cR, 0,0,0);
          cR = MFMA32(nil_, bih[ni], cR, 0,0,0);
          cI = MFMA32(arh,  bih[ni], cI, 0,0,0);
          cI = MFMA32(arh,  bil[ni], cI, 0,0,0);
          cI = MFMA32(arl,  bih[ni], cI, 0,0,0);
          cI = MFMA32(aih,  brh[ni], cI, 0,0,0);
          cI = MFMA32(aih,  brl[ni], cI, 0,0,0);
          cI = MFMA32(ail,  brh[ni], cI, 0,0,0);
          accR[mi][ni] = cR; accI[mi][ni] = cI;
        }
      }
    }
  }

  // epilogue: 32x32 C/D layout col=lane&31, row=(j&3)+8*(j>>2)+4*(lane>>5)
  const size_t OS = (size_t)RR * OUT;
  #pragma unroll
  for (int mi=0; mi<2; mi++){
    #pragma unroll
    for (int ni=0; ni<2; ni++){
      int c = colBase + wc0 + ni*32 + fr2;
      float bR = br_[c], bI = bi_[c];
      #pragma unroll
      for (int j=0; j<16; j++){
        int r = rowBase + wr0 + mi*32 + (j&3) + 8*(j>>2) + 4*fq2;
        float oR = accR[mi][ni][j] + bR;
        float oI = accI[mi][ni][j] + bI;
        if (ACT == 1){ oR = gelu_exact(oR); oI = gelu_exact(oI); }
        if (RES_MODE == 1){
          oR += resr[(size_t)r*OUT + c];
          oI += resi[(size_t)r*OUT + c];
        } else if (RES_MODE == 2){
          oR += resr[(size_t)r*(2*OUT) + 2*c];
          oI += resr[(size_t)r*(2*OUT) + 2*c + 1];
        }
        if (OUT_MODE == 0){
          outr[(size_t)r*OUT + c] = oR;
          outi[(size_t)r*OUT + c] = oI;
        } else if (OUT_MODE == 1){
          outr[(size_t)r*(2*OUT) + 2*c]     = oR;
          outr[(size_t)r*(2*OUT) + 2*c + 1] = oI;
        } else if (OUT_MODE == 2){
          // QKV split bf16: Q,K -> [bh][n][64]; V -> [bh][64][n]
          int part = c / EE; int win = c - part*EE;
          int hh = win >> 6, dd = win & 63;
          int bq = r >> 10, nq = r & 1023;
          int bhh = bq*HH + hh;
          size_t idx = (part < 2) ? (((size_t)bhh*NN + nq)*DD + dd)
                                  : (((size_t)bhh*DD + dd)*NN + nq);
          bf16_t* bas = osplit + (size_t)part*4*SZH;
          bf16_t hR,lR,hI,lI;
          split2(oR,hR,lR); split2(oI,hI,lI);
          bas[idx]         = hR;
          bas[SZH + idx]   = lR;
          bas[2*SZH + idx] = hI;
          bas[3*SZH + idx] = lI;
        } else {
          // tiled bf16 planes for next GEMM (Ko = OUT>>3)
          bf16_t hR,lR,hI,lI;
          split2(oR,hR,lR); split2(oI,hI,lI);
          size_t ad = tiled_ad(r, c, OUT>>3);
          osplit[ad]        = hR;
          osplit[OS + ad]   = lR;
          osplit[2*OS + ad] = hI;
          osplit[3*OS + ad] = lI;
        }
      }
    }
  }
}

// ---------------- complex flash attention via MFMA ----------------
// unchanged core (16x16x32); epilogue writes tiled bf16 planes for proj.
__global__ __launch_bounds__(256) void cattn_mfma(
    const bf16_t* __restrict__ qs,
    bf16_t* __restrict__ ao4)
{
  __shared__ bf16_t Krh[32][72], Krl[32][72], Kih[32][72], Kil[32][72];
  __shared__ bf16_t Vrh[64][40], Vrl[64][40], Vih[64][40], Vil[64][40];
  __shared__ bf16_t Pl[4][16][40];

  const int tid = threadIdx.x;
  const int lane = tid & 63, wid = tid >> 6;
  const int fr = lane & 15, fq = lane >> 4;
  const int qt = blockIdx.x, bh = blockIdx.y;
  const int b = bh / HH, h = bh - b*HH;

  const bf16_t* Qb = qs;
  const bf16_t* Kb = qs + 4*SZH;
  const bf16_t* Vb = qs + 8*SZH;

  const int qrow = qt*64 + wid*16 + fr;
  bf16x8 q_rh[2], q_rl[2], q_ih[2], q_il[2], nq_ih[2], nq_il[2];
  #pragma unroll
  for (int c=0;c<2;c++){
    size_t o = ((size_t)bh*NN + qrow)*DD + c*32 + fq*8;
    q_rh[c] = *(const bf16x8*)(Qb + 0*SZH + o);
    q_rl[c] = *(const bf16x8*)(Qb + 1*SZH + o);
    q_ih[c] = *(const bf16x8*)(Qb + 2*SZH + o);
    q_il[c] = *(const bf16x8*)(Qb + 3*SZH + o);
    nq_ih[c] = negv(q_ih[c]);
    nq_il[c] = negv(q_il[c]);
  }

  f32x4 accOr[4], accOi[4];
  #pragma unroll
  for (int df=0;df<4;df++){ accOr[df] = (f32x4)0.f; accOi[df] = (f32x4)0.f; }
  float m[4] = {0.f,0.f,0.f,0.f}, l[4] = {0.f,0.f,0.f,0.f};

  const int skr = tid >> 3, skc = (tid & 7) * 8;
  const int svr = tid >> 2, svc = (tid & 3) * 8;

  for (int kt = 0; kt < NN/32; kt++){
    __syncthreads();
    {
      size_t kb = ((size_t)bh*NN + kt*32 + skr)*DD + skc;
      *(bf16x8*)&Krh[skr][skc] = *(const bf16x8*)(Kb + 0*SZH + kb);
      *(bf16x8*)&Krl[skr][skc] = *(const bf16x8*)(Kb + 1*SZH + kb);
      *(bf16x8*)&Kih[skr][skc] = *(const bf16x8*)(Kb + 2*SZH + kb);
      *(bf16x8*)&Kil[skr][skc] = *(const bf16x8*)(Kb + 3*SZH + kb);
      size_t vb = ((size_t)bh*DD + svr)*NN + kt*32 + svc;
      *(bf16x8*)&Vrh[svr][svc] = *(const bf16x8*)(Vb + 0*SZH + vb);
      *(bf16x8*)&Vrl[svr][svc] = *(const bf16x8*)(Vb + 1*SZH + vb);
      *(bf16x8*)&Vih[svr][svc] = *(const bf16x8*)(Vb + 2*SZH + vb);
      *(bf16x8*)&Vil[svr][svc] = *(const bf16x8*)(Vb + 3*SZH + vb);
    }
    __syncthreads();

    f32x4 sr[2], si[2];
    #pragma unroll
    for (int f=0; f<2; f++){
      f32x4 r = (f32x4)0.f, im = (f32x4)0.f;
      #pragma unroll
      for (int c=0; c<2; c++){
        const int kr_ = f*16 + fr, co = c*32 + fq*8;
        bf16x8 krh = *(const bf16x8*)&Krh[kr_][co];
        bf16x8 krl = *(const bf16x8*)&Krl[kr_][co];
        bf16x8 kih = *(const bf16x8*)&Kih[kr_][co];
        bf16x8 kil = *(const bf16x8*)&Kil[kr_][co];
        r = MFMA16(q_rh[c], krh, r, 0,0,0);
        r = MFMA16(q_rh[c], krl, r, 0,0,0);
        r = MFMA16(q_rl[c], krh, r, 0,0,0);
        r = MFMA16(q_ih[c], kih, r, 0,0,0);
        r = MFMA16(q_ih[c], kil, r, 0,0,0);
        r = MFMA16(q_il[c], kih, r, 0,0,0);
        im = MFMA16(q_rh[c], kih, im, 0,0,0);
        im = MFMA16(q_rh[c], kil, im, 0,0,0);
        im = MFMA16(q_rl[c], kih, im, 0,0,0);
        im = MFMA16(nq_ih[c], krh, im, 0,0,0);
        im = MFMA16(nq_ih[c], krl, im, 0,0,0);
        im = MFMA16(nq_il[c], krh, im, 0,0,0);
      }
      sr[f] = r; si[f] = im;
    }

    float mg[2][4];
    #pragma unroll
    for (int f=0; f<2; f++)
      #pragma unroll
      for (int j=0; j<4; j++){
        float a = sr[f][j], c2 = si[f][j];
        mg[f][j] = sqrtf(fmaf(a,a, fmaf(c2,c2, 1e-8f))) * 0.125f;
      }
    float al[4];
    #pragma unroll
    for (int j=0; j<4; j++){
      float mx = fmaxf(mg[0][j], mg[1][j]);
      mx = fmaxf(mx, __shfl_xor(mx, 1, 64));
      mx = fmaxf(mx, __shfl_xor(mx, 2, 64));
      mx = fmaxf(mx, __shfl_xor(mx, 4, 64));
      mx = fmaxf(mx, __shfl_xor(mx, 8, 64));
      float nm = fmaxf(m[j], mx);
      al[j] = __expf(m[j] - nm);
      m[j] = nm;
    }
    unsigned pk[4]; float psum[4];
    #pragma unroll
    for (int j=0; j<4; j++){
      float p0 = __expf(mg[0][j] - m[j]);
      float p1 = __expf(mg[1][j] - m[j]);
      bf16_t b0 = (bf16_t)p0, b1 = (bf16_t)p1;
      pk[j] = (unsigned)__builtin_bit_cast(unsigned short, b0)
            | ((unsigned)__builtin_bit_cast(unsigned short, b1) << 16);
      psum[j] = (float)b0 + (float)b1;
    }
    #pragma unroll
    for (int j=0; j<4; j++){
      float s = psum[j];
      s += __shfl_xor(s, 1, 64);
      s += __shfl_xor(s, 2, 64);
      s += __shfl_xor(s, 4, 64);
      s += __shfl_xor(s, 8, 64);
      l[j] = l[j]*al[j] + s;
      #pragma unroll
      for (int df=0; df<4; df++){ accOr[df][j] *= al[j]; accOi[df][j] *= al[j]; }
    }
    #pragma unroll
    for (int j=0; j<4; j++){
      unsigned partner = (unsigned)__shfl_xor((int)pk[j], 1, 64);
      unsigned word; int kcol;
      if ((fr & 1) == 0){
        word = (pk[j] & 0xFFFFu) | (partner << 16);
        kcol = fr;
      } else {
        word = (partner >> 16) | (pk[j] & 0xFFFF0000u);
        kcol = 15 + fr;
      }
      int q = fq*4 + j;
      *(unsigned*)&Pl[wid][q][kcol] = word;
    }
    __syncthreads();

    bf16x8 pa = *(const bf16x8*)&Pl[wid][fr][fq*8];
    #pragma unroll
    for (int df=0; df<4; df++){
      const int dr = df*16 + fr, co = fq*8;
      bf16x8 vrh = *(const bf16x8*)&Vrh[dr][co];
      bf16x8 vrl = *(const bf16x8*)&Vrl[dr][co];
      bf16x8 vih = *(const bf16x8*)&Vih[dr][co];
      bf16x8 vil = *(const bf16x8*)&Vil[dr][co];
      f32x4 cr = accOr[df], ci = accOi[df];
      cr = MFMA16(pa, vrh, cr, 0,0,0);
      cr = MFMA16(pa, vrl, cr, 0,0,0);
      ci = MFMA16(pa, vih, ci, 0,0,0);
      ci = MFMA16(pa, vil, ci, 0,0,0);
      accOr[df] = cr; accOi[df] = ci;
    }
  }

  // epilogue: out frag col=d=df*16+fr, row=q=fq*4+j -> tiled bf16 planes (Ko=96)
  const size_t PS = (size_t)RR*EE;
  #pragma unroll
  for (int j=0; j<4; j++){
    float invl = 1.0f / l[j];
    int r = b*NN + qt*64 + wid*16 + fq*4 + j;
    #pragma unroll
    for (int df=0; df<4; df++){
      int c = h*DD + df*16 + fr;
      float vR = accOr[df][j] * invl;
      float vI = accOi[df][j] * invl;
      bf16_t hR,lR,hI,lI;
      split2(vR,hR,lR); split2(vI,hI,lI);
      size_t ad = tiled_ad(r, c, 96);
      ao4[ad]        = hR;
      ao4[PS + ad]   = lR;
      ao4[2*PS + ad] = hI;
      ao4[3*PS + ad] = lI;
    }
  }
}

extern "C" void kernel_launch(void* const* d_in, const int* in_sizes, int n_in,
                              void* d_out, int out_size, void* d_ws, size_t ws_size,
                              hipStream_t stream) {
  const float* x       = (const float*)d_in[0];
  const float* g1      = (const float*)d_in[1];
  const float* b1      = (const float*)d_in[2];
  const float* g2      = (const float*)d_in[3];
  const float* b2      = (const float*)d_in[4];
  const float* qkv_wr  = (const float*)d_in[5];
  const float* qkv_wi  = (const float*)d_in[6];
  const float* qkv_br  = (const float*)d_in[7];
  const float* qkv_bi  = (const float*)d_in[8];
  const float* proj_wr = (const float*)d_in[9];
  const float* proj_wi = (const float*)d_in[10];
  const float* proj_br = (const float*)d_in[11];
  const float* proj_bi = (const float*)d_in[12];
  const float* m1_wr   = (const float*)d_in[13];
  const float* m1_wi   = (const float*)d_in[14];
  const float* m1_br   = (const float*)d_in[15];
  const float* m1_bi   = (const float*)d_in[16];
  const float* m2_wr   = (const float*)d_in[17];
  const float* m2_wi   = (const float*)d_in[18];
  const float* m2_br   = (const float*)d_in[19];
  const float* m2_bi   = (const float*)d_in[20];

  float* ws = (float*)d_ws;
  const size_t RE = (size_t)RR * EE;
  // region A [0,2RE): xn tiled planes, then ao tiled planes
  bf16_t* xn4 = (bf16_t*)ws;
  bf16_t* ao4 = (bf16_t*)ws;
  // region B [2RE,8RE): qsplit (12*SZH bf16); later xn2 planes [2RE,4RE) + h planes [4RE,8RE)
  bf16_t* qsplit = (bf16_t*)(ws + 2*RE);
  bf16_t* xn2_4  = (bf16_t*)(ws + 2*RE);
  bf16_t* h4     = (bf16_t*)(ws + 4*RE);
  // region C [8RE,10RE): x1 planar f32
  float* x1_r  = ws + 8*RE;     float* x1_i  = ws + 9*RE;

  // 1. LN1 -> xn tiled planes
  cln_kernel<<<RR, 256, 0, stream>>>(x, nullptr, nullptr, g1, b1, xn4, 0);
  // 2. QKV -> attention split arrays
  cgemm_v2<0,0,2><<<dim3(18,32), 256, 0, stream>>>(
      xn4, qkv_wr, qkv_wi, qkv_br, qkv_bi,
      nullptr, nullptr, nullptr, nullptr, qsplit, EE, 3*EE);
  // 3. attention -> ao tiled planes
  cattn_mfma<<<dim3(16,48), 256, 0, stream>>>(qsplit, ao4);
  // 4. proj + residual(x interleaved) -> x1 planar
  cgemm_v2<0,2,0><<<dim3(6,32), 256, 0, stream>>>(
      ao4, proj_wr, proj_wi, proj_br, proj_bi,
      x, nullptr, x1_r, x1_i, nullptr, EE, EE);
  // 5. LN2 -> xn2 tiled planes
  cln_kernel<<<RR, 256, 0, stream>>>(nullptr, x1_r, x1_i, g2, b2, xn2_4, 1);
  // 6. MLP1 + gelu -> h tiled planes
  cgemm_v2<1,0,3><<<dim3(12,32), 256, 0, stream>>>(
      xn2_4, m1_wr, m1_wi, m1_br, m1_bi,
      nullptr, nullptr, nullptr, nullptr, h4, EE, MLPH);
  // 7. MLP2 + residual(x1 planar) -> d_out interleaved
  cgemm_v2<0,1,1><<<dim3(6,32), 256, 0, stream>>>(
      h4, m2_wr, m2_wi, m2_br, m2_bi,
      x1_r, x1_i, (float*)d_out, nullptr, nullptr, MLPH, EE);
}

// Round 8
// 884.095 us; speedup vs baseline: 1.3226x; 1.3226x over previous
//
#include <hip/hip_runtime.h>
#include <math.h>

#define BB 4
#define NN 1024
#define EE 768
#define HH 12
#define DD 64
#define MLPH 1536
#define RR (BB*NN)
#define SZH ((size_t)48*1024*64)   // elements per split attention array

constexpr float EPS = 1e-6f;

typedef __bf16 bf16_t;
typedef bf16_t bf16x8 __attribute__((ext_vector_type(8)));
typedef bf16_t bf16x4 __attribute__((ext_vector_type(4)));
typedef float  f32x4  __attribute__((ext_vector_type(4)));
typedef unsigned short us8 __attribute__((ext_vector_type(8)));

#define MFMA16 __builtin_amdgcn_mfma_f32_16x16x32_bf16

__device__ __forceinline__ float gelu_exact(float x){
  return 0.5f * x * (1.0f + erff(x * 0.70710678118654752440f));
}

__device__ __forceinline__ bf16x8 negv(bf16x8 v){
  us8 u = __builtin_bit_cast(us8, v);
  u ^= (unsigned short)0x8000;
  return __builtin_bit_cast(bf16x8, u);
}

__device__ __forceinline__ void split2(float f, bf16_t& h, bf16_t& l){
  h = (bf16_t)f; l = (bf16_t)(f - (float)h);
}

// split fp32x4 -> hi/lo bf16x4, store to LDS (two 8B stores)
__device__ __forceinline__ void cvtstore(bf16_t* hp, bf16_t* lp, f32x4 v){
  bf16x4 h, l;
  #pragma unroll
  for (int i=0;i<4;i++){
    float f = v[i];
    bf16_t hb = (bf16_t)f;
    h[i] = hb;
    l[i] = (bf16_t)(f - (float)hb);
  }
  *(bf16x4*)hp = h;
  *(bf16x4*)lp = l;
}

// async global->LDS, 16B per lane; lds dest wave-uniform (HW adds lane*16)
__device__ __forceinline__ void gload_lds16(const bf16_t* g, bf16_t* l){
  __builtin_amdgcn_global_load_lds(
      (const __attribute__((address_space(1))) void*)g,
      (__attribute__((address_space(3))) void*)l, 16, 0, 0);
}

// tiled-plane address: plane[((row>>4)*Ko + (col>>3))*128 + (row&15)*8 + (col&7)]
__device__ __forceinline__ size_t tiled_ad(int r, int c, int Ko){
  return (((size_t)(r>>4)*Ko + (c>>3))*16 + (r&15))*8 + (c&7);
}

// ---------------- complex layernorm -> 4 tiled bf16 planes ----------------
__global__ __launch_bounds__(256) void cln_kernel(
    const float* __restrict__ inI,
    const float* __restrict__ inR, const float* __restrict__ inIm,
    const float* __restrict__ gamma, const float* __restrict__ beta,
    bf16_t* __restrict__ out4, int mode)
{
  const size_t PS = (size_t)RR*EE;
  int row = blockIdx.x;
  int t = threadIdx.x;
  __shared__ float sbuf[4];
  float vr[3], vi[3], mg[3];
  #pragma unroll
  for (int j=0;j<3;j++){
    int e = t + 256*j;
    float a, b;
    if (mode == 0){
      a = inI[(size_t)row*(2*EE) + 2*e];
      b = inI[(size_t)row*(2*EE) + 2*e + 1];
    } else {
      a = inR[(size_t)row*EE + e];
      b = inIm[(size_t)row*EE + e];
    }
    vr[j]=a; vi[j]=b;
    mg[j] = sqrtf(a*a + b*b + EPS);
  }
  int lane = t & 63, wv = t >> 6;
  float s = mg[0]+mg[1]+mg[2];
  #pragma unroll
  for (int o=32;o>0;o>>=1) s += __shfl_down(s, o, 64);
  if (lane==0) sbuf[wv] = s;
  __syncthreads();
  float mean = (sbuf[0]+sbuf[1]+sbuf[2]+sbuf[3]) * (1.0f/EE);
  __syncthreads();
  float v = 0.f;
  #pragma unroll
  for (int j=0;j<3;j++){ float d = mg[j]-mean; v += d*d; }
  #pragma unroll
  for (int o=32;o>0;o>>=1) v += __shfl_down(v, o, 64);
  if (lane==0) sbuf[wv] = v;
  __syncthreads();
  float var = (sbuf[0]+sbuf[1]+sbuf[2]+sbuf[3]) * (1.0f/EE);
  float inv = 1.0f / sqrtf(var + EPS);
  #pragma unroll
  for (int j=0;j<3;j++){
    int e = t + 256*j;
    float scale = ((mg[j]-mean) * inv) / (mg[j] + EPS);
    float oR = gamma[2*e]   * (vr[j]*scale) + beta[2*e];
    float oI = gamma[2*e+1] * (vi[j]*scale) + beta[2*e+1];
    bf16_t hR,lR,hI,lI;
    split2(oR,hR,lR); split2(oI,hI,lI);
    size_t ad = tiled_ad(row, e, 96);
    out4[ad]        = hR;
    out4[PS + ad]   = lR;
    out4[2*PS + ad] = hI;
    out4[3*PS + ad] = lI;
  }
}

// ---------------- complex GEMM v3: 16x16x32, BM=128 BN=64 BK=32 -----------
// A: 4 tiled bf16 planes staged via global_load_lds (layout-matched 1KB chunks).
// B (weights): fp32, register-staged + cvt-split, conflict-free write map.
// LDS 48KB -> 3 blocks/CU. 4 waves 2x2, each 64x32 (4x2 frags of 16x16).
// OUT_MODE: 0 planar f32, 1 interleaved f32, 2 QKV-attention split, 3 tiled bf16
template<int ACT, int RES_MODE, int OUT_MODE>
__global__ __launch_bounds__(256, 3) void cgemm_v3(
    const bf16_t* __restrict__ a4,
    const float* __restrict__ wr, const float* __restrict__ wi,
    const float* __restrict__ br_, const float* __restrict__ bi_,
    const float* __restrict__ resr, const float* __restrict__ resi,
    float* __restrict__ outr, float* __restrict__ outi,
    bf16_t* __restrict__ osplit,
    int K, int OUT)
{
  __shared__ bf16_t Al[16384];  // 4 planes x (8 panels x 4 oct x 16 x 8)
  __shared__ bf16_t Bl[8192];   // 4 planes x (4 panels x 4 oct x 16 x 8)

  const int tid = threadIdx.x;
  const int wid = tid >> 6, lane = tid & 63;
  const int rowBase = blockIdx.y * 128, colBase = blockIdx.x * 64;
  const int Ko = K >> 3;
  const size_t AS = (size_t)RR * K;

  // B staging map (verified 0-conflict in r7): quarter-wave -> 16 distinct banks
  const int b_so = (tid >> 4) & 3;            // k-octet 0..3
  const int b_se = (tid & 1) * 4;             // elem 0 or 4
  const int b_r0 = ((tid & 15) >> 1) + 8*wid; // row 0..31 (+32*it)

  // frag coords (16x16)
  const int fr = lane & 15, fq = lane >> 4;
  const int wr0 = (wid >> 1) * 64, wc0 = (wid & 1) * 32;

  f32x4 accR[4][2], accI[4][2];
  #pragma unroll
  for (int mi=0;mi<4;mi++)
    #pragma unroll
    for (int ni=0;ni<2;ni++){ accR[mi][ni] = (f32x4)0.f; accI[mi][ni] = (f32x4)0.f; }

  f32x4 pBr[2], pBi[2];
  auto LOADB = [&](int k0){
    #pragma unroll
    for (int it=0; it<2; it++){
      size_t ro = (size_t)(colBase + b_r0 + it*32)*K + k0 + b_so*8 + b_se;
      pBr[it] = *(const f32x4*)(wr + ro);
      pBi[it] = *(const f32x4*)(wi + ro);
    }
  };
  LOADB(0);

  for (int k0 = 0; k0 < K; k0 += 32){
    const int o0 = k0 >> 3;
    __syncthreads();   // previous compute done reading LDS
    // B: split+store (conflict-free)
    #pragma unroll
    for (int it=0; it<2; it++){
      int r = b_r0 + it*32;
      int off = ((r>>4)*4 + b_so)*128 + (r&15)*8 + b_se;
      cvtstore(&Bl[off],      &Bl[2048+off], pBr[it]);
      cvtstore(&Bl[4096+off], &Bl[6144+off], pBi[it]);
    }
    // A: async 1KB chunk loads, 8 per wave (4 planes x 2 panels)
    #pragma unroll
    for (int q=0; q<4; q++){
      #pragma unroll
      for (int s2=0; s2<2; s2++){
        int pi = wid*2 + s2;
        const bf16_t* g = a4 + (size_t)q*AS
            + ((size_t)(blockIdx.y*8 + pi)*Ko + o0)*128 + lane*8;
        gload_lds16(g, &Al[q*4096 + pi*512]);
      }
    }
    __syncthreads();   // drains ds_write + global_load_lds
    if (k0 + 32 < K) LOADB(k0 + 32);

    // B frags (hoisted): panel pb = (wid&1)*2 + ni
    bf16x8 brh[2], brl[2], bih[2], bil[2];
    #pragma unroll
    for (int ni=0; ni<2; ni++){
      int off = (((wid&1)*2 + ni)*4 + fq)*128 + fr*8;
      brh[ni] = *(const bf16x8*)&Bl[off];
      brl[ni] = *(const bf16x8*)&Bl[2048+off];
      bih[ni] = *(const bf16x8*)&Bl[4096+off];
      bil[ni] = *(const bf16x8*)&Bl[6144+off];
    }
    #pragma unroll
    for (int mi=0; mi<4; mi++){
      int off = (((wid>>1)*4 + mi)*4 + fq)*128 + fr*8;
      bf16x8 arh = *(const bf16x8*)&Al[off];
      bf16x8 arl = *(const bf16x8*)&Al[4096+off];
      bf16x8 aih = *(const bf16x8*)&Al[8192+off];
      bf16x8 ail = *(const bf16x8*)&Al[12288+off];
      bf16x8 nih = negv(aih), nil_ = negv(ail);
      #pragma unroll
      for (int ni=0; ni<2; ni++){
        f32x4 cR = accR[mi][ni], cI = accI[mi][ni];
        cR = MFMA16(arh,  brh[ni], cR, 0,0,0);
        cR = MFMA16(arh,  brl[ni], cR, 0,0,0);
        cR = MFMA16(arl,  brh[ni], cR, 0,0,0);
        cR = MFMA16(nih,  bih[ni], cR, 0,0,0);
        cR = MFMA16(nih,  bil[ni], cR, 0,0,0);
        cR = MFMA16(nil_, bih[ni], cR, 0,0,0);
        cI = MFMA16(arh,  bih[ni], cI, 0,0,0);
        cI = MFMA16(arh,  bil[ni], cI, 0,0,0);
        cI = MFMA16(arl,  bih[ni], cI, 0,0,0);
        cI = MFMA16(aih,  brh[ni], cI, 0,0,0);
        cI = MFMA16(aih,  brl[ni], cI, 0,0,0);
        cI = MFMA16(ail,  brh[ni], cI, 0,0,0);
        accR[mi][ni] = cR; accI[mi][ni] = cI;
      }
    }
  }

  // epilogue: 16x16 C/D layout col=fr, row=fq*4+j
  const size_t OS = (size_t)RR * OUT;
  #pragma unroll
  for (int mi=0; mi<4; mi++){
    #pragma unroll
    for (int ni=0; ni<2; ni++){
      int c = colBase + wc0 + ni*16 + fr;
      float bR = br_[c], bI = bi_[c];
      #pragma unroll
      for (int j=0; j<4; j++){
        int r = rowBase + wr0 + mi*16 + fq*4 + j;
        float oR = accR[mi][ni][j] + bR;
        float oI = accI[mi][ni][j] + bI;
        if (ACT == 1){ oR = gelu_exact(oR); oI = gelu_exact(oI); }
        if (RES_MODE == 1){
          oR += resr[(size_t)r*OUT + c];
          oI += resi[(size_t)r*OUT + c];
        } else if (RES_MODE == 2){
          oR += resr[(size_t)r*(2*OUT) + 2*c];
          oI += resr[(size_t)r*(2*OUT) + 2*c + 1];
        }
        if (OUT_MODE == 0){
          outr[(size_t)r*OUT + c] = oR;
          outi[(size_t)r*OUT + c] = oI;
        } else if (OUT_MODE == 1){
          outr[(size_t)r*(2*OUT) + 2*c]     = oR;
          outr[(size_t)r*(2*OUT) + 2*c + 1] = oI;
        } else if (OUT_MODE == 2){
          // QKV split bf16: Q,K -> [bh][n][64]; V -> [bh][64][n]
          int part = c / EE; int win = c - part*EE;
          int hh = win >> 6, dd = win & 63;
          int bq = r >> 10, nq = r & 1023;
          int bhh = bq*HH + hh;
          size_t idx = (part < 2) ? (((size_t)bhh*NN + nq)*DD + dd)
                                  : (((size_t)bhh*DD + dd)*NN + nq);
          bf16_t* bas = osplit + (size_t)part*4*SZH;
          bf16_t hR,lR,hI,lI;
          split2(oR,hR,lR); split2(oI,hI,lI);
          bas[idx]         = hR;
          bas[SZH + idx]   = lR;
          bas[2*SZH + idx] = hI;
          bas[3*SZH + idx] = lI;
        } else {
          // tiled bf16 planes for next GEMM (Ko = OUT>>3)
          bf16_t hR,lR,hI,lI;
          split2(oR,hR,lR); split2(oI,hI,lI);
          size_t ad = tiled_ad(r, c, OUT>>3);
          osplit[ad]        = hR;
          osplit[OS + ad]   = lR;
          osplit[2*OS + ad] = hI;
          osplit[3*OS + ad] = lI;
        }
      }
    }
  }
}

// ---------------- complex flash attention via MFMA (unchanged) -------------
__global__ __launch_bounds__(256) void cattn_mfma(
    const bf16_t* __restrict__ qs,
    bf16_t* __restrict__ ao4)
{
  __shared__ bf16_t Krh[32][72], Krl[32][72], Kih[32][72], Kil[32][72];
  __shared__ bf16_t Vrh[64][40], Vrl[64][40], Vih[64][40], Vil[64][40];
  __shared__ bf16_t Pl[4][16][40];

  const int tid = threadIdx.x;
  const int lane = tid & 63, wid = tid >> 6;
  const int fr = lane & 15, fq = lane >> 4;
  const int qt = blockIdx.x, bh = blockIdx.y;
  const int b = bh / HH, h = bh - b*HH;

  const bf16_t* Qb = qs;
  const bf16_t* Kb = qs + 4*SZH;
  const bf16_t* Vb = qs + 8*SZH;

  const int qrow = qt*64 + wid*16 + fr;
  bf16x8 q_rh[2], q_rl[2], q_ih[2], q_il[2], nq_ih[2], nq_il[2];
  #pragma unroll
  for (int c=0;c<2;c++){
    size_t o = ((size_t)bh*NN + qrow)*DD + c*32 + fq*8;
    q_rh[c] = *(const bf16x8*)(Qb + 0*SZH + o);
    q_rl[c] = *(const bf16x8*)(Qb + 1*SZH + o);
    q_ih[c] = *(const bf16x8*)(Qb + 2*SZH + o);
    q_il[c] = *(const bf16x8*)(Qb + 3*SZH + o);
    nq_ih[c] = negv(q_ih[c]);
    nq_il[c] = negv(q_il[c]);
  }

  f32x4 accOr[4], accOi[4];
  #pragma unroll
  for (int df=0;df<4;df++){ accOr[df] = (f32x4)0.f; accOi[df] = (f32x4)0.f; }
  float m[4] = {0.f,0.f,0.f,0.f}, l[4] = {0.f,0.f,0.f,0.f};

  const int skr = tid >> 3, skc = (tid & 7) * 8;
  const int svr = tid >> 2, svc = (tid & 3) * 8;

  for (int kt = 0; kt < NN/32; kt++){
    __syncthreads();
    {
      size_t kb = ((size_t)bh*NN + kt*32 + skr)*DD + skc;
      *(bf16x8*)&Krh[skr][skc] = *(const bf16x8*)(Kb + 0*SZH + kb);
      *(bf16x8*)&Krl[skr][skc] = *(const bf16x8*)(Kb + 1*SZH + kb);
      *(bf16x8*)&Kih[skr][skc] = *(const bf16x8*)(Kb + 2*SZH + kb);
      *(bf16x8*)&Kil[skr][skc] = *(const bf16x8*)(Kb + 3*SZH + kb);
      size_t vb = ((size_t)bh*DD + svr)*NN + kt*32 + svc;
      *(bf16x8*)&Vrh[svr][svc] = *(const bf16x8*)(Vb + 0*SZH + vb);
      *(bf16x8*)&Vrl[svr][svc] = *(const bf16x8*)(Vb + 1*SZH + vb);
      *(bf16x8*)&Vih[svr][svc] = *(const bf16x8*)(Vb + 2*SZH + vb);
      *(bf16x8*)&Vil[svr][svc] = *(const bf16x8*)(Vb + 3*SZH + vb);
    }
    __syncthreads();

    f32x4 sr[2], si[2];
    #pragma unroll
    for (int f=0; f<2; f++){
      f32x4 r = (f32x4)0.f, im = (f32x4)0.f;
      #pragma unroll
      for (int c=0; c<2; c++){
        const int kr_ = f*16 + fr, co = c*32 + fq*8;
        bf16x8 krh = *(const bf16x8*)&Krh[kr_][co];
        bf16x8 krl = *(const bf16x8*)&Krl[kr_][co];
        bf16x8 kih = *(const bf16x8*)&Kih[kr_][co];
        bf16x8 kil = *(const bf16x8*)&Kil[kr_][co];
        r = MFMA16(q_rh[c], krh, r, 0,0,0);
        r = MFMA16(q_rh[c], krl, r, 0,0,0);
        r = MFMA16(q_rl[c], krh, r, 0,0,0);
        r = MFMA16(q_ih[c], kih, r, 0,0,0);
        r = MFMA16(q_ih[c], kil, r, 0,0,0);
        r = MFMA16(q_il[c], kih, r, 0,0,0);
        im = MFMA16(q_rh[c], kih, im, 0,0,0);
        im = MFMA16(q_rh[c], kil, im, 0,0,0);
        im = MFMA16(q_rl[c], kih, im, 0,0,0);
        im = MFMA16(nq_ih[c], krh, im, 0,0,0);
        im = MFMA16(nq_ih[c], krl, im, 0,0,0);
        im = MFMA16(nq_il[c], krh, im, 0,0,0);
      }
      sr[f] = r; si[f] = im;
    }

    float mg[2][4];
    #pragma unroll
    for (int f=0; f<2; f++)
      #pragma unroll
      for (int j=0; j<4; j++){
        float a = sr[f][j], c2 = si[f][j];
        mg[f][j] = sqrtf(fmaf(a,a, fmaf(c2,c2, 1e-8f))) * 0.125f;
      }
    float al[4];
    #pragma unroll
    for (int j=0; j<4; j++){
      float mx = fmaxf(mg[0][j], mg[1][j]);
      mx = fmaxf(mx, __shfl_xor(mx, 1, 64));
      mx = fmaxf(mx, __shfl_xor(mx, 2, 64));
      mx = fmaxf(mx, __shfl_xor(mx, 4, 64));
      mx = fmaxf(mx, __shfl_xor(mx, 8, 64));
      float nm = fmaxf(m[j], mx);
      al[j] = __expf(m[j] - nm);
      m[j] = nm;
    }
    unsigned pk[4]; float psum[4];
    #pragma unroll
    for (int j=0; j<4; j++){
      float p0 = __expf(mg[0][j] - m[j]);
      float p1 = __expf(mg[1][j] - m[j]);
      bf16_t b0 = (bf16_t)p0, b1 = (bf16_t)p1;
      pk[j] = (unsigned)__builtin_bit_cast(unsigned short, b0)
            | ((unsigned)__builtin_bit_cast(unsigned short, b1) << 16);
      psum[j] = (float)b0 + (float)b1;
    }
    #pragma unroll
    for (int j=0; j<4; j++){
      float s = psum[j];
      s += __shfl_xor(s, 1, 64);
      s += __shfl_xor(s, 2, 64);
      s += __shfl_xor(s, 4, 64);
      s += __shfl_xor(s, 8, 64);
      l[j] = l[j]*al[j] + s;
      #pragma unroll
      for (int df=0; df<4; df++){ accOr[df][j] *= al[j]; accOi[df][j] *= al[j]; }
    }
    #pragma unroll
    for (int j=0; j<4; j++){
      unsigned partner = (unsigned)__shfl_xor((int)pk[j], 1, 64);
      unsigned word; int kcol;
      if ((fr & 1) == 0){
        word = (pk[j] & 0xFFFFu) | (partner << 16);
        kcol = fr;
      } else {
        word = (partner >> 16) | (pk[j] & 0xFFFF0000u);
        kcol = 15 + fr;
      }
      int q = fq*4 + j;
      *(unsigned*)&Pl[wid][q][kcol] = word;
    }
    __syncthreads();

    bf16x8 pa = *(const bf16x8*)&Pl[wid][fr][fq*8];
    #pragma unroll
    for (int df=0; df<4; df++){
      const int dr = df*16 + fr, co = fq*8;
      bf16x8 vrh = *(const bf16x8*)&Vrh[dr][co];
      bf16x8 vrl = *(const bf16x8*)&Vrl[dr][co];
      bf16x8 vih = *(const bf16x8*)&Vih[dr][co];
      bf16x8 vil = *(const bf16x8*)&Vil[dr][co];
      f32x4 cr = accOr[df], ci = accOi[df];
      cr = MFMA16(pa, vrh, cr, 0,0,0);
      cr = MFMA16(pa, vrl, cr, 0,0,0);
      ci = MFMA16(pa, vih, ci, 0,0,0);
      ci = MFMA16(pa, vil, ci, 0,0,0);
      accOr[df] = cr; accOi[df] = ci;
    }
  }

  // epilogue -> tiled bf16 planes (Ko=96)
  const size_t PS = (size_t)RR*EE;
  #pragma unroll
  for (int j=0; j<4; j++){
    float invl = 1.0f / l[j];
    int r = b*NN + qt*64 + wid*16 + fq*4 + j;
    #pragma unroll
    for (int df=0; df<4; df++){
      int c = h*DD + df*16 + fr;
      float vR = accOr[df][j] * invl;
      float vI = accOi[df][j] * invl;
      bf16_t hR,lR,hI,lI;
      split2(vR,hR,lR); split2(vI,hI,lI);
      size_t ad = tiled_ad(r, c, 96);
      ao4[ad]        = hR;
      ao4[PS + ad]   = lR;
      ao4[2*PS + ad] = hI;
      ao4[3*PS + ad] = lI;
    }
  }
}

extern "C" void kernel_launch(void* const* d_in, const int* in_sizes, int n_in,
                              void* d_out, int out_size, void* d_ws, size_t ws_size,
                              hipStream_t stream) {
  const float* x       = (const float*)d_in[0];
  const float* g1      = (const float*)d_in[1];
  const float* b1      = (const float*)d_in[2];
  const float* g2      = (const float*)d_in[3];
  const float* b2      = (const float*)d_in[4];
  const float* qkv_wr  = (const float*)d_in[5];
  const float* qkv_wi  = (const float*)d_in[6];
  const float* qkv_br  = (const float*)d_in[7];
  const float* qkv_bi  = (const float*)d_in[8];
  const float* proj_wr = (const float*)d_in[9];
  const float* proj_wi = (const float*)d_in[10];
  const float* proj_br = (const float*)d_in[11];
  const float* proj_bi = (const float*)d_in[12];
  const float* m1_wr   = (const float*)d_in[13];
  const float* m1_wi   = (const float*)d_in[14];
  const float* m1_br   = (const float*)d_in[15];
  const float* m1_bi   = (const float*)d_in[16];
  const float* m2_wr   = (const float*)d_in[17];
  const float* m2_wi   = (const float*)d_in[18];
  const float* m2_br   = (const float*)d_in[19];
  const float* m2_bi   = (const float*)d_in[20];

  float* ws = (float*)d_ws;
  const size_t RE = (size_t)RR * EE;
  // region A [0,2RE): xn tiled planes, then ao tiled planes
  bf16_t* xn4 = (bf16_t*)ws;
  bf16_t* ao4 = (bf16_t*)ws;
  // region B [2RE,8RE): qsplit; later xn2 planes [2RE,4RE) + h planes [4RE,8RE)
  bf16_t* qsplit = (bf16_t*)(ws + 2*RE);
  bf16_t* xn2_4  = (bf16_t*)(ws + 2*RE);
  bf16_t* h4     = (bf16_t*)(ws + 4*RE);
  // region C [8RE,10RE): x1 planar f32
  float* x1_r  = ws + 8*RE;     float* x1_i  = ws + 9*RE;

  // 1. LN1 -> xn tiled planes
  cln_kernel<<<RR, 256, 0, stream>>>(x, nullptr, nullptr, g1, b1, xn4, 0);
  // 2. QKV -> attention split arrays
  cgemm_v3<0,0,2><<<dim3(36,32), 256, 0, stream>>>(
      xn4, qkv_wr, qkv_wi, qkv_br, qkv_bi,
      nullptr, nullptr, nullptr, nullptr, qsplit, EE, 3*EE);
  // 3. attention -> ao tiled planes
  cattn_mfma<<<dim3(16,48), 256, 0, stream>>>(qsplit, ao4);
  // 4. proj + residual(x interleaved) -> x1 planar
  cgemm_v3<0,2,0><<<dim3(12,32), 256, 0, stream>>>(
      ao4, proj_wr, proj_wi, proj_br, proj_bi,
      x, nullptr, x1_r, x1_i, nullptr, EE, EE);
  // 5. LN2 -> xn2 tiled planes
  cln_kernel<<<RR, 256, 0, stream>>>(nullptr, x1_r, x1_i, g2, b2, xn2_4, 1);
  // 6. MLP1 + gelu -> h tiled planes
  cgemm_v3<1,0,3><<<dim3(24,32), 256, 0, stream>>>(
      xn2_4, m1_wr, m1_wi, m1_br, m1_bi,
      nullptr, nullptr, nullptr, nullptr, h4, EE, MLPH);
  // 7. MLP2 + residual(x1 planar) -> d_out interleaved
  cgemm_v3<0,1,1><<<dim3(12,32), 256, 0, stream>>>(
      h4, m2_wr, m2_wi, m2_br, m2_bi,
      x1_r, x1_i, (float*)d_out, nullptr, nullptr, MLPH, EE);
}